// Round 8
// baseline (297.461 us; speedup 1.0000x reference)
//
#include <hip/hip_runtime.h>
#include <math.h>

// Causal self-attention, B=4, T=2048, E=1024, H=16, D=64. fp32 in/out,
// bf16 MFMA internally.

typedef __bf16 bf16x8 __attribute__((ext_vector_type(8)));
typedef float f32x4 __attribute__((ext_vector_type(4)));
typedef unsigned int u32x4 __attribute__((ext_vector_type(4)));
typedef unsigned int uint;
typedef unsigned short ushort;

#define B_ 4
#define T_ 2048
#define E_ 1024
#define H_ 16
#define D_ 64
#define BT_ (B_ * T_)   // 8192

__device__ __forceinline__ f32x4 mfma16(bf16x8 a, bf16x8 b, f32x4 c) {
  return __builtin_amdgcn_mfma_f32_16x16x32_bf16(a, b, c, 0, 0, 0);
}

// async global->LDS, 16B per lane. LDS dest linear: base + lane*16.
__device__ __forceinline__ void gl_lds16(void* lds, const void* g) {
  __builtin_amdgcn_global_load_lds(
      (__attribute__((address_space(1))) unsigned int*)g,
      (__attribute__((address_space(3))) unsigned int*)lds, 16, 0, 0);
}

__device__ __forceinline__ uint pkbf(float a, float b) {
  ushort ux = __builtin_bit_cast(ushort, (__bf16)a);
  ushort uy = __builtin_bit_cast(ushort, (__bf16)b);
  return (uint)ux | ((uint)uy << 16);
}

// ---------------------------------------------------------------- convert
__global__ __launch_bounds__(256) void cvt_bf16(const float* __restrict__ in,
                                                __bf16* __restrict__ out, int n) {
  int i = (blockIdx.x * 256 + threadIdx.x) * 8;
  if (i >= n) return;
  float4 a = *(const float4*)&in[i];
  float4 b = *(const float4*)&in[i + 4];
  bf16x8 o;
  o[0] = (__bf16)a.x; o[1] = (__bf16)a.y; o[2] = (__bf16)a.z; o[3] = (__bf16)a.w;
  o[4] = (__bf16)b.x; o[5] = (__bf16)b.y; o[6] = (__bf16)b.z; o[7] = (__bf16)b.w;
  *(bf16x8*)&out[i] = o;
}

// ---------------------------------------------------------------- GEMM (NT)
// C[m][n] = sum_k A[m][k]*B[n][k] + bias.  A:[M][K] bf16, B:[N][K] bf16.
template <int MODE>
__global__ __launch_bounds__(256) void gemm_nt(const __bf16* __restrict__ A,
                                               const __bf16* __restrict__ Bm,
                                               const float* __restrict__ bias,
                                               void* __restrict__ out,
                                               int M, int N, int K) {
  __shared__ __bf16 sA[128 * 32];
  __shared__ __bf16 sB[128 * 32];
  const int tid = threadIdx.x;
  const int lane = tid & 63;
  const int wv = tid >> 6;
  const int wr = (wv >> 1) << 6;
  const int wc = (wv & 1) << 6;
  const int fr = lane & 15;
  const int fo = (lane >> 4) << 3;
  const int g = lane >> 4;
  const int m0 = blockIdx.y * 128;
  const int n0 = blockIdx.x * 128;

  f32x4 acc[4][4] = {};

  const __bf16* aRow = A + (size_t)(m0 + (tid >> 2)) * K + ((tid & 3) << 3);
  const __bf16* bRow = Bm + (size_t)(n0 + (tid >> 2)) * K + ((tid & 3) << 3);

  for (int kt = 0; kt < K; kt += 32) {
    gl_lds16(&sA[(size_t)tid * 8], aRow + kt);
    gl_lds16(&sA[(size_t)(256 + tid) * 8], aRow + (size_t)64 * K + kt);
    gl_lds16(&sB[(size_t)tid * 8], bRow + kt);
    gl_lds16(&sB[(size_t)(256 + tid) * 8], bRow + (size_t)64 * K + kt);
    __syncthreads();
    bf16x8 af[4], bq[4];
#pragma unroll
    for (int i = 0; i < 4; i++) af[i] = *(const bf16x8*)&sA[(wr + i * 16 + fr) * 32 + fo];
#pragma unroll
    for (int i = 0; i < 4; i++) bq[i] = *(const bf16x8*)&sB[(wc + i * 16 + fr) * 32 + fo];
#pragma unroll
    for (int i = 0; i < 4; i++)
#pragma unroll
      for (int j = 0; j < 4; j++) acc[i][j] = mfma16(af[i], bq[j], acc[i][j]);
    __syncthreads();
  }

#pragma unroll
  for (int i = 0; i < 4; i++) {
#pragma unroll
    for (int j = 0; j < 4; j++) {
#pragma unroll
      for (int r = 0; r < 4; r++) {
        const int m = m0 + wr + i * 16 + g * 4 + r;
        const int n = n0 + wc + j * 16 + fr;
        float v = acc[i][j][r];
        if constexpr (MODE == 0) {
          v += bias[n];
          const int b = m >> 11, t = m & (T_ - 1);
          const int h = n >> 6, d = n & 63;
          ((__bf16*)out)[(((size_t)b * H_ + h) * T_ + t) * D_ + d] = (__bf16)v;
        } else if constexpr (MODE == 1) {
          v += bias[m];
          const int b = n >> 11, t = n & (T_ - 1);
          const int h = m >> 6, d = m & 63;
          ((__bf16*)out)[(((size_t)b * H_ + h) * D_ + d) * T_ + t] = (__bf16)v;
        } else {
          v += bias[n];
          ((float*)out)[(size_t)m * N + n] = v;
        }
      }
    }
  }
}

// ---------------------------------------------------------------- attention
// Q,K: [B,H,T,D] bf16.  Vt: [B,H,D,T] bf16.  O: [B,T,H,D] bf16.
// ONE wave per block, ONE q-tile (32 rows) per block, KVBLK=64, no LDS/
// barriers; K/V frags from global (L2-hot via head->XCD pinning: block k ->
// xcd k&7 serves heads bh%8==k&7). 4096 blocks = 16 waves/CU => 4 waves/SIMD
// for latency hiding (r4/r7 plateaued at 2 waves/SIMD, grid-capped).
// Heavy-first ordering: qt = 63-(j&63) so 32-tile blocks dispatch first and
// the tail is filled by 1-tile blocks. Swapped QK^T keeps softmax in-lane;
// P redistributed to A-frag layout via ds_bpermute. Defer-max (T13) with
// partial-max vote (fast path has NO cross-lane ops).
__global__ __launch_bounds__(64, 2) void attn_fwd(const __bf16* __restrict__ Q,
                                                  const __bf16* __restrict__ Kg,
                                                  const __bf16* __restrict__ Vt,
                                                  __bf16* __restrict__ O) {
  const int lane = threadIdx.x;
  const int fr = lane & 15;
  const int g = lane >> 4;
  const int k = blockIdx.x;
  const int j = k >> 3;
  const int bh = (k & 7) + ((j >> 6) << 3);  // head pinned to xcd = bh%8
  const int qt = 63 - (j & 63);              // heavy blocks dispatch first
  const __bf16* Qp = Q + (size_t)bh * T_ * D_;
  const __bf16* Kp = Kg + (size_t)bh * T_ * D_;
  const __bf16* Vp = Vt + (size_t)bh * D_ * T_;
  const float SCL = 0.125f * 1.44269504088896f;  // 1/sqrt(D) * log2(e)
  const int addrA = (fr + 32 * (g & 1)) * 4;     // bpermute base (bytes)
  const int b = bh >> 4, h = bh & 15;

  auto loadK = [&](bf16x8 (&kf)[4][2], int kv0) {
#pragma unroll
    for (int kvf = 0; kvf < 4; ++kvf)
#pragma unroll
      for (int kc = 0; kc < 2; ++kc)
        kf[kvf][kc] =
            *(const bf16x8*)&Kp[(size_t)(kv0 + kvf * 16 + fr) * D_ + kc * 32 + g * 8];
  };

  const int qw = qt * 32;
  const int ntile = (qt >> 1) + 1;

  // Q B-frags: lane holds Q[qw+mf*16+fr][kc*32 + g*8 + j]
  bf16x8 qf[2][2];
#pragma unroll
  for (int mf = 0; mf < 2; mf++)
#pragma unroll
    for (int kc = 0; kc < 2; kc++)
      qf[mf][kc] =
          *(const bf16x8*)&Qp[(size_t)(qw + mf * 16 + fr) * D_ + kc * 32 + g * 8];

  f32x4 acc[2][4] = {};                    // O[q=qw+mf*16+g*4+r][d=nd*16+fr]
  float mrun[2] = {-INFINITY, -INFINITY};  // per-lane q-row (fr) stats
  float lrun[2] = {0.f, 0.f};

  bf16x8 kf[4][2];
  loadK(kf, 0);

#pragma unroll 1
  for (int kt = 0; kt < ntile; ++kt) {
    const int kv0 = kt << 6;

    // V B-frags for this tile (consumed after softmax -> latency hidden)
    bf16x8 vf[4][2];
#pragma unroll
    for (int nd = 0; nd < 4; ++nd)
#pragma unroll
      for (int kc = 0; kc < 2; ++kc)
        vf[nd][kc] =
            *(const bf16x8*)&Vp[(size_t)(nd * 16 + fr) * T_ + kv0 + kc * 32 + g * 8];

    // ---- S^T = K . Q^T
    f32x4 st[4][2] = {};  // [kvf][mf]
    __builtin_amdgcn_s_setprio(1);
#pragma unroll
    for (int kvf = 0; kvf < 4; ++kvf)
#pragma unroll
      for (int mf = 0; mf < 2; ++mf) {
        st[kvf][mf] = mfma16(kf[kvf][0], qf[mf][0], st[kvf][mf]);
        st[kvf][mf] = mfma16(kf[kvf][1], qf[mf][1], st[kvf][mf]);
      }
    __builtin_amdgcn_s_setprio(0);

    // prefetch next tile's K (hidden under softmax; compiler renames regs)
    if (kt + 1 < ntile) loadK(kf, (kt + 1) << 6);

    // ---- causal mask (only the last tile straddles the diagonal)
    if (kt == ntile - 1) {
#pragma unroll
      for (int kvf = 0; kvf < 4; ++kvf)
#pragma unroll
        for (int mf = 0; mf < 2; ++mf)
#pragma unroll
          for (int r = 0; r < 4; ++r)
            if (kv0 + kvf * 16 + g * 4 + r > qw + mf * 16 + fr)
              st[kvf][mf][r] = -INFINITY;
    }

    // ---- online softmax (per-lane row) + P pack + redistribution
    uint W[2][2][4];  // [mf][kc][word]
#pragma unroll
    for (int mf = 0; mf < 2; ++mf) {
      // per-lane PARTIAL max over this lane's 16 S values (max3 tree)
      float rm[4];
#pragma unroll
      for (int kvf = 0; kvf < 4; ++kvf)
        rm[kvf] = fmaxf(fmaxf(st[kvf][mf][0], st[kvf][mf][1]),
                        fmaxf(st[kvf][mf][2], st[kvf][mf][3]));
      float rmax = fmaxf(fmaxf(rm[0], rm[1]), fmaxf(rm[2], rm[3])) * SCL;

      // defer-max fast path: if every lane's partial is within the bound,
      // the true row max is too -> keep mrun, NO cross-lane reduce at all.
      if (!__all(rmax - mrun[mf] <= 8.f)) {
        // slow path: full cross-lane reduce + rescale
        float rfull = fmaxf(rmax, __shfl_xor(rmax, 16, 64));
        rfull = fmaxf(rfull, __shfl_xor(rfull, 32, 64));
        const float mn = fmaxf(mrun[mf], rfull);
        const float corr = exp2f(mrun[mf] - mn);  // 0 on first tile
        mrun[mf] = mn;
        lrun[mf] *= corr;
        float cg[4];
#pragma unroll
        for (int r = 0; r < 4; ++r) cg[r] = __shfl(corr, g * 4 + r, 64);
#pragma unroll
        for (int nd = 0; nd < 4; ++nd)
#pragma unroll
          for (int r = 0; r < 4; ++r) acc[mf][nd][r] *= cg[r];
      }

      float p[4][4];
      float ls = 0.f;
#pragma unroll
      for (int kvf = 0; kvf < 4; ++kvf)
#pragma unroll
        for (int r = 0; r < 4; ++r) {
          p[kvf][r] = exp2f(fmaf(st[kvf][mf][r], SCL, -mrun[mf]));
          ls += p[kvf][r];
        }
      lrun[mf] += ls;

      // pack to bf16 pairs: w[kvf][h] = kv (16kvf+4g+2h, +1)
      uint w[4][2];
#pragma unroll
      for (int kvf = 0; kvf < 4; ++kvf) {
        w[kvf][0] = pkbf(p[kvf][0], p[kvf][1]);
        w[kvf][1] = pkbf(p[kvf][2], p[kvf][3]);
      }
      // redistribute to A-frag: lane needs kv = 32kc + 8g + 2m (,+1)
#pragma unroll
      for (int kc = 0; kc < 2; ++kc)
#pragma unroll
        for (int m = 0; m < 4; ++m) {
          const int a = addrA + (m >> 1) * 64;
          int t0 = __builtin_amdgcn_ds_bpermute(a, (int)w[2 * kc][m & 1]);
          int t1 = __builtin_amdgcn_ds_bpermute(a, (int)w[2 * kc + 1][m & 1]);
          W[mf][kc][m] = (uint)((g >> 1) ? t1 : t0);
        }
    }

    // ---- O += P V
    __builtin_amdgcn_s_setprio(1);
#pragma unroll
    for (int kc = 0; kc < 2; ++kc) {
      bf16x8 pa[2];
#pragma unroll
      for (int mf = 0; mf < 2; ++mf) {
        u32x4 t;
        t[0] = W[mf][kc][0]; t[1] = W[mf][kc][1];
        t[2] = W[mf][kc][2]; t[3] = W[mf][kc][3];
        pa[mf] = __builtin_bit_cast(bf16x8, t);
      }
#pragma unroll
      for (int nd = 0; nd < 4; ++nd)
#pragma unroll
        for (int mf = 0; mf < 2; ++mf)
          acc[mf][nd] = mfma16(pa[mf], vf[nd][kc], acc[mf][nd]);
    }
    __builtin_amdgcn_s_setprio(0);
  }

  // ---- epilogue: full row sums, divide, store [B,T,H,D]
#pragma unroll
  for (int mf = 0; mf < 2; ++mf) {
    lrun[mf] += __shfl_xor(lrun[mf], 16, 64);
    lrun[mf] += __shfl_xor(lrun[mf], 32, 64);
  }
#pragma unroll
  for (int mf = 0; mf < 2; ++mf) {
    float linv[4];
#pragma unroll
    for (int r = 0; r < 4; ++r) linv[r] = 1.f / __shfl(lrun[mf], g * 4 + r, 64);
#pragma unroll
    for (int nd = 0; nd < 4; ++nd)
#pragma unroll
      for (int r = 0; r < 4; ++r) {
        const int t = qw + mf * 16 + g * 4 + r;
        O[(((size_t)b * T_ + t) * H_ + h) * D_ + nd * 16 + fr] =
            (__bf16)(acc[mf][nd][r] * linv[r]);
      }
  }
}

// ---------------------------------------------------------------- launcher
extern "C" void kernel_launch(void* const* d_in, const int* in_sizes, int n_in,
                              void* d_out, int out_size, void* d_ws, size_t ws_size,
                              hipStream_t stream) {
  const float* x  = (const float*)d_in[0];
  const float* Wq = (const float*)d_in[1];
  const float* bq = (const float*)d_in[2];
  const float* Wk = (const float*)d_in[3];
  const float* bk = (const float*)d_in[4];
  const float* Wv = (const float*)d_in[5];
  const float* bv = (const float*)d_in[6];
  const float* Wo = (const float*)d_in[7];
  const float* bo = (const float*)d_in[8];

  char* w = (char*)d_ws;
  __bf16* xb  = (__bf16*)w; w += (size_t)BT_ * E_ * 2;
  __bf16* Wqb = (__bf16*)w; w += (size_t)E_ * E_ * 2;
  __bf16* Wkb = (__bf16*)w; w += (size_t)E_ * E_ * 2;
  __bf16* Wvb = (__bf16*)w; w += (size_t)E_ * E_ * 2;
  __bf16* Wob = (__bf16*)w; w += (size_t)E_ * E_ * 2;
  __bf16* Qb  = (__bf16*)w; w += (size_t)BT_ * E_ * 2;
  __bf16* Kb  = (__bf16*)w; w += (size_t)BT_ * E_ * 2;
  __bf16* Vtb = (__bf16*)w; w += (size_t)BT_ * E_ * 2;
  __bf16* Ob  = (__bf16*)w; w += (size_t)BT_ * E_ * 2;

  cvt_bf16<<<(BT_ * E_) / 2048, 256, 0, stream>>>(x, xb, BT_ * E_);
  cvt_bf16<<<(E_ * E_) / 2048, 256, 0, stream>>>(Wq, Wqb, E_ * E_);
  cvt_bf16<<<(E_ * E_) / 2048, 256, 0, stream>>>(Wk, Wkb, E_ * E_);
  cvt_bf16<<<(E_ * E_) / 2048, 256, 0, stream>>>(Wv, Wvb, E_ * E_);
  cvt_bf16<<<(E_ * E_) / 2048, 256, 0, stream>>>(Wo, Wob, E_ * E_);

  gemm_nt<0><<<dim3(E_ / 128, BT_ / 128), 256, 0, stream>>>(xb, Wqb, bq, Qb, BT_, E_, E_);
  gemm_nt<0><<<dim3(E_ / 128, BT_ / 128), 256, 0, stream>>>(xb, Wkb, bk, Kb, BT_, E_, E_);
  gemm_nt<1><<<dim3(BT_ / 128, E_ / 128), 256, 0, stream>>>(Wvb, xb, bv, Vtb, E_, BT_, E_);

  attn_fwd<<<4096, 64, 0, stream>>>(Qb, Kb, Vtb, Ob);

  gemm_nt<2><<<dim3(E_ / 128, BT_ / 128), 256, 0, stream>>>(Ob, Wob, bo, d_out, BT_, E_, E_);
}

// Round 9
// 238.876 us; speedup vs baseline: 1.2453x; 1.2453x over previous
//
#include <hip/hip_runtime.h>
#include <math.h>

// Causal self-attention, B=4, T=2048, E=1024, H=16, D=64. fp32 in/out,
// bf16 MFMA internally.

typedef __bf16 bf16x8 __attribute__((ext_vector_type(8)));
typedef float f32x4 __attribute__((ext_vector_type(4)));
typedef unsigned int u32x4 __attribute__((ext_vector_type(4)));
typedef unsigned int uint;
typedef unsigned short ushort;

#define B_ 4
#define T_ 2048
#define E_ 1024
#define H_ 16
#define D_ 64
#define BT_ (B_ * T_)   // 8192

__device__ __forceinline__ f32x4 mfma16(bf16x8 a, bf16x8 b, f32x4 c) {
  return __builtin_amdgcn_mfma_f32_16x16x32_bf16(a, b, c, 0, 0, 0);
}

// async global->LDS, 16B per lane. LDS dest linear: base + lane*16.
__device__ __forceinline__ void gl_lds16(void* lds, const void* g) {
  __builtin_amdgcn_global_load_lds(
      (__attribute__((address_space(1))) unsigned int*)g,
      (__attribute__((address_space(3))) unsigned int*)lds, 16, 0, 0);
}

__device__ __forceinline__ uint pkbf(float a, float b) {
  ushort ux = __builtin_bit_cast(ushort, (__bf16)a);
  ushort uy = __builtin_bit_cast(ushort, (__bf16)b);
  return (uint)ux | ((uint)uy << 16);
}

// ---------------------------------------------------------------- convert
__global__ __launch_bounds__(256) void cvt_bf16(const float* __restrict__ in,
                                                __bf16* __restrict__ out, int n) {
  int i = (blockIdx.x * 256 + threadIdx.x) * 8;
  if (i >= n) return;
  float4 a = *(const float4*)&in[i];
  float4 b = *(const float4*)&in[i + 4];
  bf16x8 o;
  o[0] = (__bf16)a.x; o[1] = (__bf16)a.y; o[2] = (__bf16)a.z; o[3] = (__bf16)a.w;
  o[4] = (__bf16)b.x; o[5] = (__bf16)b.y; o[6] = (__bf16)b.z; o[7] = (__bf16)b.w;
  *(bf16x8*)&out[i] = o;
}

// ---------------------------------------------------------------- GEMM (NT)
// C[m][n] = sum_k A[m][k]*B[n][k] + bias.  A:[M][K] bf16, B:[N][K] bf16.
template <int MODE>
__global__ __launch_bounds__(256) void gemm_nt(const __bf16* __restrict__ A,
                                               const __bf16* __restrict__ Bm,
                                               const float* __restrict__ bias,
                                               void* __restrict__ out,
                                               int M, int N, int K) {
  __shared__ __bf16 sA[128 * 32];
  __shared__ __bf16 sB[128 * 32];
  const int tid = threadIdx.x;
  const int lane = tid & 63;
  const int wv = tid >> 6;
  const int wr = (wv >> 1) << 6;
  const int wc = (wv & 1) << 6;
  const int fr = lane & 15;
  const int fo = (lane >> 4) << 3;
  const int g = lane >> 4;
  const int m0 = blockIdx.y * 128;
  const int n0 = blockIdx.x * 128;

  f32x4 acc[4][4] = {};

  const __bf16* aRow = A + (size_t)(m0 + (tid >> 2)) * K + ((tid & 3) << 3);
  const __bf16* bRow = Bm + (size_t)(n0 + (tid >> 2)) * K + ((tid & 3) << 3);

  for (int kt = 0; kt < K; kt += 32) {
    gl_lds16(&sA[(size_t)tid * 8], aRow + kt);
    gl_lds16(&sA[(size_t)(256 + tid) * 8], aRow + (size_t)64 * K + kt);
    gl_lds16(&sB[(size_t)tid * 8], bRow + kt);
    gl_lds16(&sB[(size_t)(256 + tid) * 8], bRow + (size_t)64 * K + kt);
    __syncthreads();
    bf16x8 af[4], bq[4];
#pragma unroll
    for (int i = 0; i < 4; i++) af[i] = *(const bf16x8*)&sA[(wr + i * 16 + fr) * 32 + fo];
#pragma unroll
    for (int i = 0; i < 4; i++) bq[i] = *(const bf16x8*)&sB[(wc + i * 16 + fr) * 32 + fo];
#pragma unroll
    for (int i = 0; i < 4; i++)
#pragma unroll
      for (int j = 0; j < 4; j++) acc[i][j] = mfma16(af[i], bq[j], acc[i][j]);
    __syncthreads();
  }

#pragma unroll
  for (int i = 0; i < 4; i++) {
#pragma unroll
    for (int j = 0; j < 4; j++) {
#pragma unroll
      for (int r = 0; r < 4; r++) {
        const int m = m0 + wr + i * 16 + g * 4 + r;
        const int n = n0 + wc + j * 16 + fr;
        float v = acc[i][j][r];
        if constexpr (MODE == 0) {
          v += bias[n];
          const int b = m >> 11, t = m & (T_ - 1);
          const int h = n >> 6, d = n & 63;
          ((__bf16*)out)[(((size_t)b * H_ + h) * T_ + t) * D_ + d] = (__bf16)v;
        } else if constexpr (MODE == 1) {
          v += bias[m];
          const int b = n >> 11, t = n & (T_ - 1);
          const int h = m >> 6, d = m & 63;
          ((__bf16*)out)[(((size_t)b * H_ + h) * D_ + d) * T_ + t] = (__bf16)v;
        } else {
          v += bias[n];
          ((float*)out)[(size_t)m * N + n] = v;
        }
      }
    }
  }
}

// ---------------------------------------------------------------- attention
// Q,K: [B,H,T,D] bf16.  Vt: [B,H,D,T] bf16.  O: [B,T,H,D] bf16.
// r6-r8 established the limiter is shared L2 bandwidth on K/V re-reads
// (per-wave private streams ~26 TB/s demand vs ~34 TB/s ceiling; more waves
// made it worse). Fix: 4-wave blocks covering one 128-row q-supertile (each
// wave keeps its own 32 rows -> NO cross-wave softmax), K/V staged ONCE per
// block into LDS (4x less L2 traffic) with XOR-chunk swizzle (pre-swizzled
// global source + swizzled ds_read_b128, rule #21; verified in r2).
// 2-phase pipeline: issue stage(t+1) before compute(t); single trailing
// barrier per tile (its vmcnt drain lands after ~900cy of compute).
// Supertile pairing (s,15-s) => every block exactly 34 tiles. Head->XCD
// pinning kept. Compute path (swapped QK^T, partial-vote defer-max,
// bpermute P-redistribution, epilogue) is r7-verbatim.
__global__ __launch_bounds__(256) void attn_fwd(const __bf16* __restrict__ Q,
                                                const __bf16* __restrict__ Kg,
                                                const __bf16* __restrict__ Vt,
                                                __bf16* __restrict__ O) {
  __shared__ __bf16 sK[2][64 * 64];  // [kv][d], chunk-swizzled
  __shared__ __bf16 sV[2][64 * 64];  // [d][kv], chunk-swizzled
  const int tid = threadIdx.x;
  const int lane = tid & 63;
  const int wv = tid >> 6;  // wave 0..3 -> q rows 32*wv..+32 of the supertile
  const int fr = lane & 15;
  const int g = lane >> 4;
  const int k = blockIdx.x;
  const int bh = (k & 7) | ((k >> 6) << 3);  // head pinned to xcd = bh%8
  const int pr = (k >> 3) & 7;               // supertile pair index
  const __bf16* Qp = Q + (size_t)bh * T_ * D_;
  const __bf16* Kp = Kg + (size_t)bh * T_ * D_;
  const __bf16* Vp = Vt + (size_t)bh * D_ * T_;
  const float SCL = 0.125f * 1.44269504088896f;  // 1/sqrt(D) * log2(e)
  const int addrA = (fr + 32 * (g & 1)) * 4;     // bpermute base (bytes)
  const int swz = fr & 7;
  const int b = bh >> 4, h = bh & 15;

  // cooperative stage of one 64-kv tile (K: [64][64], V^T: [64][64]),
  // 16B/lane x 1024 ops, pre-swizzled global source (chunk ^= row&7).
  auto stage = [&](int buf, int kv0) {
#pragma unroll
    for (int rr = 0; rr < 2; ++rr) {
      const int idx = rr * 256 + tid;
      const int row = idx >> 3, ch = idx & 7;
      gl_lds16(&sK[buf][idx * 8],
               Kp + (size_t)(kv0 + row) * D_ + ((ch ^ (row & 7)) << 3));
      gl_lds16(&sV[buf][idx * 8],
               Vp + (size_t)row * T_ + kv0 + ((ch ^ (row & 7)) << 3));
    }
  };

#pragma unroll 1
  for (int pass = 0; pass < 2; ++pass) {
    const int s = pass ? 15 - pr : pr;   // supertile (128 q rows)
    const int qw = s * 128 + wv * 32;    // this wave's q base
    const int ntile = 2 * s + 2;

    // Q B-frags: lane holds Q[qw+mf*16+fr][kc*32 + g*8 + j]
    bf16x8 qf[2][2];
#pragma unroll
    for (int mf = 0; mf < 2; mf++)
#pragma unroll
      for (int kc = 0; kc < 2; kc++)
        qf[mf][kc] =
            *(const bf16x8*)&Qp[(size_t)(qw + mf * 16 + fr) * D_ + kc * 32 + g * 8];

    f32x4 acc[2][4] = {};                    // O[q=qw+mf*16+g*4+r][d=nd*16+fr]
    float mrun[2] = {-INFINITY, -INFINITY};  // per-lane q-row (fr) stats
    float lrun[2] = {0.f, 0.f};

    stage(0, 0);
    __syncthreads();
    int cur = 0;

#pragma unroll 1
    for (int kt = 0; kt < ntile; ++kt) {
      const int kv0 = kt << 6;
      if (kt + 1 < ntile) stage(cur ^ 1, (kt + 1) << 6);  // prefetch next

      if (kv0 <= qw + 31) {  // wave has unmasked work in this tile
        // ---- S^T = K . Q^T  (K frags from swizzled LDS)
        f32x4 st[4][2] = {};  // [kvf][mf]
        __builtin_amdgcn_s_setprio(1);
#pragma unroll
        for (int kvf = 0; kvf < 4; ++kvf) {
          const int row = kvf * 16 + fr;
          bf16x8 kf0 = *(const bf16x8*)&sK[cur][row * 64 + ((g ^ swz) << 3)];
          bf16x8 kf1 = *(const bf16x8*)&sK[cur][row * 64 + (((g + 4) ^ swz) << 3)];
#pragma unroll
          for (int mf = 0; mf < 2; ++mf) {
            st[kvf][mf] = mfma16(kf0, qf[mf][0], st[kvf][mf]);
            st[kvf][mf] = mfma16(kf1, qf[mf][1], st[kvf][mf]);
          }
        }
        __builtin_amdgcn_s_setprio(0);

        // ---- causal mask (only tiles straddling this wave's rows)
        if (kv0 + 63 > qw) {
#pragma unroll
          for (int kvf = 0; kvf < 4; ++kvf)
#pragma unroll
            for (int mf = 0; mf < 2; ++mf)
#pragma unroll
              for (int r = 0; r < 4; ++r)
                if (kv0 + kvf * 16 + g * 4 + r > qw + mf * 16 + fr)
                  st[kvf][mf][r] = -INFINITY;
        }

        // ---- online softmax (per-lane row) + P pack + redistribution
        uint W[2][2][4];  // [mf][kc][word]
#pragma unroll
        for (int mf = 0; mf < 2; ++mf) {
          float rm[4];
#pragma unroll
          for (int kvf = 0; kvf < 4; ++kvf)
            rm[kvf] = fmaxf(fmaxf(st[kvf][mf][0], st[kvf][mf][1]),
                            fmaxf(st[kvf][mf][2], st[kvf][mf][3]));
          float rmax = fmaxf(fmaxf(rm[0], rm[1]), fmaxf(rm[2], rm[3])) * SCL;

          // defer-max fast path: partial-max vote, no cross-lane ops
          if (!__all(rmax - mrun[mf] <= 8.f)) {
            float rfull = fmaxf(rmax, __shfl_xor(rmax, 16, 64));
            rfull = fmaxf(rfull, __shfl_xor(rfull, 32, 64));
            const float mn = fmaxf(mrun[mf], rfull);
            const float corr = exp2f(mrun[mf] - mn);  // 0 on first tile
            mrun[mf] = mn;
            lrun[mf] *= corr;
            float cg[4];
#pragma unroll
            for (int r = 0; r < 4; ++r) cg[r] = __shfl(corr, g * 4 + r, 64);
#pragma unroll
            for (int nd = 0; nd < 4; ++nd)
#pragma unroll
              for (int r = 0; r < 4; ++r) acc[mf][nd][r] *= cg[r];
          }

          float p[4][4];
          float ls = 0.f;
#pragma unroll
          for (int kvf = 0; kvf < 4; ++kvf)
#pragma unroll
            for (int r = 0; r < 4; ++r) {
              p[kvf][r] = exp2f(fmaf(st[kvf][mf][r], SCL, -mrun[mf]));
              ls += p[kvf][r];
            }
          lrun[mf] += ls;

          uint w[4][2];
#pragma unroll
          for (int kvf = 0; kvf < 4; ++kvf) {
            w[kvf][0] = pkbf(p[kvf][0], p[kvf][1]);
            w[kvf][1] = pkbf(p[kvf][2], p[kvf][3]);
          }
          // redistribute to A-frag: lane needs kv = 32kc + 8g + 2m (,+1)
#pragma unroll
          for (int kc = 0; kc < 2; ++kc)
#pragma unroll
            for (int m = 0; m < 4; ++m) {
              const int a = addrA + (m >> 1) * 64;
              int t0 = __builtin_amdgcn_ds_bpermute(a, (int)w[2 * kc][m & 1]);
              int t1 = __builtin_amdgcn_ds_bpermute(a, (int)w[2 * kc + 1][m & 1]);
              W[mf][kc][m] = (uint)((g >> 1) ? t1 : t0);
            }
        }

        // ---- O += P V  (V frags from swizzled LDS)
        __builtin_amdgcn_s_setprio(1);
#pragma unroll
        for (int kc = 0; kc < 2; ++kc) {
          bf16x8 pa[2];
#pragma unroll
          for (int mf = 0; mf < 2; ++mf) {
            u32x4 t;
            t[0] = W[mf][kc][0]; t[1] = W[mf][kc][1];
            t[2] = W[mf][kc][2]; t[3] = W[mf][kc][3];
            pa[mf] = __builtin_bit_cast(bf16x8, t);
          }
#pragma unroll
          for (int nd = 0; nd < 4; ++nd) {
            const int row = nd * 16 + fr;
            bf16x8 vf =
                *(const bf16x8*)&sV[cur][row * 64 + (((4 * kc + g) ^ swz) << 3)];
#pragma unroll
            for (int mf = 0; mf < 2; ++mf)
              acc[mf][nd] = mfma16(pa[mf], vf, acc[mf][nd]);
          }
        }
        __builtin_amdgcn_s_setprio(0);
      }

      __syncthreads();  // drains stage vmcnt + protects buffer swap
      cur ^= 1;
    }

    // ---- epilogue: full row sums, divide, store [B,T,H,D]
#pragma unroll
    for (int mf = 0; mf < 2; ++mf) {
      lrun[mf] += __shfl_xor(lrun[mf], 16, 64);
      lrun[mf] += __shfl_xor(lrun[mf], 32, 64);
    }
#pragma unroll
    for (int mf = 0; mf < 2; ++mf) {
      float linv[4];
#pragma unroll
      for (int r = 0; r < 4; ++r) linv[r] = 1.f / __shfl(lrun[mf], g * 4 + r, 64);
#pragma unroll
      for (int nd = 0; nd < 4; ++nd)
#pragma unroll
        for (int r = 0; r < 4; ++r) {
          const int t = qw + mf * 16 + g * 4 + r;
          O[(((size_t)b * T_ + t) * H_ + h) * D_ + nd * 16 + fr] =
              (__bf16)(acc[mf][nd][r] * linv[r]);
        }
    }
  }
}

// ---------------------------------------------------------------- launcher
extern "C" void kernel_launch(void* const* d_in, const int* in_sizes, int n_in,
                              void* d_out, int out_size, void* d_ws, size_t ws_size,
                              hipStream_t stream) {
  const float* x  = (const float*)d_in[0];
  const float* Wq = (const float*)d_in[1];
  const float* bq = (const float*)d_in[2];
  const float* Wk = (const float*)d_in[3];
  const float* bk = (const float*)d_in[4];
  const float* Wv = (const float*)d_in[5];
  const float* bv = (const float*)d_in[6];
  const float* Wo = (const float*)d_in[7];
  const float* bo = (const float*)d_in[8];

  char* w = (char*)d_ws;
  __bf16* xb  = (__bf16*)w; w += (size_t)BT_ * E_ * 2;
  __bf16* Wqb = (__bf16*)w; w += (size_t)E_ * E_ * 2;
  __bf16* Wkb = (__bf16*)w; w += (size_t)E_ * E_ * 2;
  __bf16* Wvb = (__bf16*)w; w += (size_t)E_ * E_ * 2;
  __bf16* Wob = (__bf16*)w; w += (size_t)E_ * E_ * 2;
  __bf16* Qb  = (__bf16*)w; w += (size_t)BT_ * E_ * 2;
  __bf16* Kb  = (__bf16*)w; w += (size_t)BT_ * E_ * 2;
  __bf16* Vtb = (__bf16*)w; w += (size_t)BT_ * E_ * 2;
  __bf16* Ob  = (__bf16*)w; w += (size_t)BT_ * E_ * 2;

  cvt_bf16<<<(BT_ * E_) / 2048, 256, 0, stream>>>(x, xb, BT_ * E_);
  cvt_bf16<<<(E_ * E_) / 2048, 256, 0, stream>>>(Wq, Wqb, E_ * E_);
  cvt_bf16<<<(E_ * E_) / 2048, 256, 0, stream>>>(Wk, Wkb, E_ * E_);
  cvt_bf16<<<(E_ * E_) / 2048, 256, 0, stream>>>(Wv, Wvb, E_ * E_);
  cvt_bf16<<<(E_ * E_) / 2048, 256, 0, stream>>>(Wo, Wob, E_ * E_);

  gemm_nt<0><<<dim3(E_ / 128, BT_ / 128), 256, 0, stream>>>(xb, Wqb, bq, Qb, BT_, E_, E_);
  gemm_nt<0><<<dim3(E_ / 128, BT_ / 128), 256, 0, stream>>>(xb, Wkb, bk, Kb, BT_, E_, E_);
  gemm_nt<1><<<dim3(BT_ / 128, E_ / 128), 256, 0, stream>>>(Wvb, xb, bv, Vtb, E_, BT_, E_);

  attn_fwd<<<512, 256, 0, stream>>>(Qb, Kb, Vtb, Ob);

  gemm_nt<2><<<dim3(E_ / 128, BT_ / 128), 256, 0, stream>>>(Ob, Wob, bo, d_out, BT_, E_, E_);
}